// Round 1
// baseline (1809.487 us; speedup 1.0000x reference)
//
#include <hip/hip_runtime.h>

#define NN 100000
#define NE 3200000

static inline int cdiv(long long a, int b) { return (int)((a + b - 1) / b); }

// deg[i] = 1.0 (self-loop weight)
__global__ void k_init_deg(float* deg, int n) {
    int i = blockIdx.x * blockDim.x + threadIdx.x;
    if (i < n) deg[i] = 1.0f;
}

// deg[dst[e]] += w[e]
__global__ void k_deg_scatter(const int* __restrict__ dst, const float* __restrict__ w,
                              float* deg, int E) {
    int e = blockIdx.x * blockDim.x + threadIdx.x;
    if (e < E) atomicAdd(&deg[dst[e]], w[e]);
}

// dis[i] = deg>0 ? rsqrt(deg) : 0
__global__ void k_deg_to_dis(float* deg, int n) {
    int i = blockIdx.x * blockDim.x + threadIdx.x;
    if (i < n) {
        float d = deg[i];
        deg[i] = d > 0.0f ? rsqrtf(d) : 0.0f;
    }
}

// agg[i][f] = x[i][f] * dis[i]^2   (self-loop contribution; also initializes buffer)
__global__ void k_agg_init(const float* __restrict__ x, const float* __restrict__ dis,
                           float* __restrict__ agg, int n, int F) {
    int t = blockIdx.x * blockDim.x + threadIdx.x;
    if (t < n * F) {
        int i = t / F;
        float d = dis[i];
        agg[t] = x[t] * d * d;
    }
}

// one thread per (edge, feature): agg[dst][f] += x[src][f] * dis[src]*w*dis[dst]
__global__ void k_edge_scatter(const int* __restrict__ src, const int* __restrict__ dst,
                               const float* __restrict__ w, const float* __restrict__ dis,
                               const float* __restrict__ x, float* agg, int E, int F) {
    int t = blockIdx.x * blockDim.x + threadIdx.x;
    int total = E * F;  // max 3.2M*54 = 172.8M < 2^31
    if (t < total) {
        int e = t / F;
        int f = t - e * F;
        int s = src[e];
        int d = dst[e];
        float nrm = dis[s] * w[e] * dis[d];
        atomicAdd(&agg[d * F + f], x[s * F + f] * nrm);
    }
}

// out[i][o] = relu(sum_f agg[i][f] * W[f][o] + b[o]);  W is [FIN][FOUT] row-major
template <int FIN, int FOUT>
__global__ void k_gemm_bias_relu(const float* __restrict__ agg, const float* __restrict__ W,
                                 const float* __restrict__ b, float* __restrict__ out, int n) {
    __shared__ float Ws[FIN * FOUT];
    __shared__ float bs[FOUT];
    for (int t = threadIdx.x; t < FIN * FOUT; t += blockDim.x) Ws[t] = W[t];
    for (int t = threadIdx.x; t < FOUT; t += blockDim.x) bs[t] = b[t];
    __syncthreads();
    int t = blockIdx.x * blockDim.x + threadIdx.x;
    if (t < n * FOUT) {
        int i = t / FOUT;
        int o = t - i * FOUT;
        float acc = bs[o];
        const float* row = agg + i * FIN;
#pragma unroll
        for (int f = 0; f < FIN; ++f) acc = fmaf(row[f], Ws[f * FOUT + o], acc);
        out[t] = fmaxf(acc, 0.0f);
    }
}

extern "C" void kernel_launch(void* const* d_in, const int* in_sizes, int n_in,
                              void* d_out, int out_size, void* d_ws, size_t ws_size,
                              hipStream_t stream) {
    const float* x  = (const float*)d_in[0];
    const int*   ei = (const int*)d_in[1];       // [2][NE]: row0=src, row1=dst
    const float* ew = (const float*)d_in[2];
    const float* W1 = (const float*)d_in[3];
    const float* b1 = (const float*)d_in[4];
    const float* W2 = (const float*)d_in[5];
    const float* b2 = (const float*)d_in[6];
    const float* W3 = (const float*)d_in[7];
    const float* b3 = (const float*)d_in[8];
    float* out = (float*)d_out;

    const int* src = ei;
    const int* dst = ei + NE;

    // workspace layout
    char* ws = (char*)d_ws;
    float* dis  = (float*)ws;                       // NN floats
    float* bufA = (float*)(ws + ((size_t)NN * 4 + 511) / 512 * 512);   // NN*54 floats
    float* bufB = bufA + (size_t)NN * 54;

    const int B = 256;

    // ---- gcn_norm: deg -> dis ----
    k_init_deg<<<cdiv(NN, B), B, 0, stream>>>(dis, NN);
    k_deg_scatter<<<cdiv(NE, B), B, 0, stream>>>(dst, ew, dis, NE);
    k_deg_to_dis<<<cdiv(NN, B), B, 0, stream>>>(dis, NN);

    // ---- layer 1: agg(x, F=9) -> gemm 9x18 -> bufB ----
    k_agg_init<<<cdiv((long long)NN * 9, B), B, 0, stream>>>(x, dis, bufA, NN, 9);
    k_edge_scatter<<<cdiv((long long)NE * 9, B), B, 0, stream>>>(src, dst, ew, dis, x, bufA, NE, 9);
    k_gemm_bias_relu<9, 18><<<cdiv((long long)NN * 18, B), B, 0, stream>>>(bufA, W1, b1, bufB, NN);

    // ---- layer 2: agg(bufB, F=18) -> gemm 18x54 -> bufB ----
    k_agg_init<<<cdiv((long long)NN * 18, B), B, 0, stream>>>(bufB, dis, bufA, NN, 18);
    k_edge_scatter<<<cdiv((long long)NE * 18, B), B, 0, stream>>>(src, dst, ew, dis, bufB, bufA, NE, 18);
    k_gemm_bias_relu<18, 54><<<cdiv((long long)NN * 54, B), B, 0, stream>>>(bufA, W2, b2, bufB, NN);

    // ---- layer 3: agg(bufB, F=54) -> gemm 54x108 -> d_out ----
    k_agg_init<<<cdiv((long long)NN * 54, B), B, 0, stream>>>(bufB, dis, bufA, NN, 54);
    k_edge_scatter<<<cdiv((long long)NE * 54, B), B, 0, stream>>>(src, dst, ew, dis, bufB, bufA, NE, 54);
    k_gemm_bias_relu<54, 108><<<cdiv((long long)NN * 108, B), B, 0, stream>>>(bufA, W3, b3, out, NN);
}

// Round 2
// 1069.699 us; speedup vs baseline: 1.6916x; 1.6916x over previous
//
#include <hip/hip_runtime.h>

#define NN 100000
#define NE 3200000
#define SCAN_CHUNK 256

static inline int cdiv(long long a, int b) { return (int)((a + b - 1) / b); }

// deg = 1.0 (self loop), cnt = 0
__global__ void k_init(float* deg, int* cnt, int n) {
    int i = blockIdx.x * blockDim.x + threadIdx.x;
    if (i < n) { deg[i] = 1.0f; cnt[i] = 0; }
}

// deg[dst] += w; cnt[dst] += 1
__global__ void k_deg_hist(const int* __restrict__ dst, const float* __restrict__ w,
                           float* deg, int* cnt, int E) {
    int e = blockIdx.x * blockDim.x + threadIdx.x;
    if (e < E) {
        int d = dst[e];
        atomicAdd(&deg[d], w[e]);
        atomicAdd(&cnt[d], 1);
    }
}

// dis = rsqrt(deg)
__global__ void k_deg_to_dis(float* deg, int n) {
    int i = blockIdx.x * blockDim.x + threadIdx.x;
    if (i < n) {
        float d = deg[i];
        deg[i] = d > 0.0f ? rsqrtf(d) : 0.0f;
    }
}

// per-chunk sums of cnt
__global__ void k_scan1(const int* __restrict__ cnt, int* part, int n) {
    __shared__ int s[SCAN_CHUNK];
    int t = threadIdx.x;
    int i = blockIdx.x * SCAN_CHUNK + t;
    s[t] = (i < n) ? cnt[i] : 0;
    __syncthreads();
    for (int d = SCAN_CHUNK / 2; d > 0; d >>= 1) {
        if (t < d) s[t] += s[t + d];
        __syncthreads();
    }
    if (t == 0) part[blockIdx.x] = s[0];
}

// exclusive scan of partials (nblk <= 512), in place
__global__ void k_scan2(int* part, int nblk) {
    __shared__ int s[512];
    int t = threadIdx.x;
    int v = (t < nblk) ? part[t] : 0;
    s[t] = v;
    __syncthreads();
    for (int d = 1; d < 512; d <<= 1) {
        int add = (t >= d) ? s[t - d] : 0;
        __syncthreads();
        s[t] += add;
        __syncthreads();
    }
    if (t < nblk) part[t] = s[t] - v;  // exclusive
}

// exclusive scan within chunk + chunk offset -> rowA (rowptr) and rowB (fill ptrs).
// NOTE: rowB aliases cnt; each thread only reads its own cnt[i] before writing.
__global__ void k_scan3(const int* __restrict__ cnt, const int* __restrict__ part,
                        int* rowA, int* rowB, int n) {
    __shared__ int s[SCAN_CHUNK];
    int t = threadIdx.x;
    int i = blockIdx.x * SCAN_CHUNK + t;
    int v = (i < n) ? cnt[i] : 0;
    s[t] = v;
    __syncthreads();
    for (int d = 1; d < SCAN_CHUNK; d <<= 1) {
        int add = (t >= d) ? s[t - d] : 0;
        __syncthreads();
        s[t] += add;
        __syncthreads();
    }
    if (i < n) {
        int val = part[blockIdx.x] + s[t] - v;  // exclusive prefix
        rowA[i] = val;
        rowB[i] = val;
        if (i == n - 1) rowA[n] = val + v;  // total = NE
    }
}

// scatter edges into CSR slots; record = (src, norm) packed 8B
__global__ void k_build(const int* __restrict__ src, const int* __restrict__ dst,
                        const float* __restrict__ w, const float* __restrict__ dis,
                        int* fill, int2* __restrict__ e2, int E) {
    int e = blockIdx.x * blockDim.x + threadIdx.x;
    if (e >= E) return;
    int s = src[e];
    int d = dst[e];
    int pos = atomicAdd(&fill[d], 1);
    float nrm = dis[s] * w[e] * dis[d];
    e2[pos] = make_int2(s, __float_as_int(nrm));
}

// gather-aggregate: thread (i,f): acc = x[i][f]*dis[i]^2 + sum_e x[src_e][f]*norm_e
template <int F>
__global__ void k_agg(const float* __restrict__ xin, const float* __restrict__ dis,
                      const int* __restrict__ rowptr, const int2* __restrict__ e2,
                      float* __restrict__ agg, int n) {
    int t = blockIdx.x * blockDim.x + threadIdx.x;
    if (t >= n * F) return;
    int i = t / F;
    int f = t - i * F;
    float d = dis[i];
    float acc = xin[i * F + f] * d * d;
    int e0 = rowptr[i];
    int e1 = rowptr[i + 1];
    for (int e = e0; e < e1; ++e) {
        int2 p = e2[e];
        acc = fmaf(xin[p.x * F + f], __int_as_float(p.y), acc);
    }
    agg[t] = acc;
}

// out[i][o] = relu(sum_f agg[i][f] * W[f][o] + b[o])
template <int FIN, int FOUT>
__global__ void k_gemm_bias_relu(const float* __restrict__ agg, const float* __restrict__ W,
                                 const float* __restrict__ b, float* __restrict__ out, int n) {
    __shared__ float Ws[FIN * FOUT];
    __shared__ float bs[FOUT];
    for (int t = threadIdx.x; t < FIN * FOUT; t += blockDim.x) Ws[t] = W[t];
    for (int t = threadIdx.x; t < FOUT; t += blockDim.x) bs[t] = b[t];
    __syncthreads();
    int t = blockIdx.x * blockDim.x + threadIdx.x;
    if (t < n * FOUT) {
        int i = t / FOUT;
        int o = t - i * FOUT;
        float acc = bs[o];
        const float* row = agg + i * FIN;
#pragma unroll
        for (int f = 0; f < FIN; ++f) acc = fmaf(row[f], Ws[f * FOUT + o], acc);
        out[t] = fmaxf(acc, 0.0f);
    }
}

extern "C" void kernel_launch(void* const* d_in, const int* in_sizes, int n_in,
                              void* d_out, int out_size, void* d_ws, size_t ws_size,
                              hipStream_t stream) {
    const float* x  = (const float*)d_in[0];
    const int*   ei = (const int*)d_in[1];  // [2][NE]: row0=src, row1=dst
    const float* ew = (const float*)d_in[2];
    const float* W1 = (const float*)d_in[3];
    const float* b1 = (const float*)d_in[4];
    const float* W2 = (const float*)d_in[5];
    const float* b2 = (const float*)d_in[6];
    const float* W3 = (const float*)d_in[7];
    const float* b3 = (const float*)d_in[8];
    float* out = (float*)d_out;

    const int* src = ei;
    const int* dst = ei + NE;

    // workspace layout (512B aligned chunks)
    char* ws = (char*)d_ws;
    size_t off = 0;
    auto alloc = [&](size_t bytes) {
        char* p = ws + off;
        off += (bytes + 511) / 512 * 512;
        return p;
    };
    float* dis  = (float*)alloc((size_t)NN * 4);
    int*   rowA = (int*)alloc((size_t)(NN + 1) * 4);
    int*   rowB = (int*)alloc((size_t)(NN + 1) * 4);  // cnt -> fill ptrs
    int*   part = (int*)alloc(512 * 4);
    int2*  e2   = (int2*)alloc((size_t)NE * 8);
    float* bufA = (float*)alloc((size_t)NN * 54 * 4);
    float* bufB = (float*)alloc((size_t)NN * 54 * 4);

    const int B = 256;
    const int NBLK = cdiv(NN, SCAN_CHUNK);  // 391

    // ---- norm + CSR build ----
    k_init<<<cdiv(NN, B), B, 0, stream>>>(dis, rowB, NN);
    k_deg_hist<<<cdiv(NE, B), B, 0, stream>>>(dst, ew, dis, rowB, NE);
    k_deg_to_dis<<<cdiv(NN, B), B, 0, stream>>>(dis, NN);
    k_scan1<<<NBLK, SCAN_CHUNK, 0, stream>>>(rowB, part, NN);
    k_scan2<<<1, 512, 0, stream>>>(part, NBLK);
    k_scan3<<<NBLK, SCAN_CHUNK, 0, stream>>>(rowB, part, rowA, rowB, NN);
    k_build<<<cdiv(NE, B), B, 0, stream>>>(src, dst, ew, dis, rowB, e2, NE);

    // ---- layer 1: agg(x, F=9) -> gemm 9x18 -> bufB ----
    k_agg<9><<<cdiv((long long)NN * 9, B), B, 0, stream>>>(x, dis, rowA, e2, bufA, NN);
    k_gemm_bias_relu<9, 18><<<cdiv((long long)NN * 18, B), B, 0, stream>>>(bufA, W1, b1, bufB, NN);

    // ---- layer 2: agg(bufB, F=18) -> gemm 18x54 -> bufB ----
    k_agg<18><<<cdiv((long long)NN * 18, B), B, 0, stream>>>(bufB, dis, rowA, e2, bufA, NN);
    k_gemm_bias_relu<18, 54><<<cdiv((long long)NN * 54, B), B, 0, stream>>>(bufA, W2, b2, bufB, NN);

    // ---- layer 3: agg(bufB, F=54) -> gemm 54x108 -> d_out ----
    k_agg<54><<<cdiv((long long)NN * 54, B), B, 0, stream>>>(bufB, dis, rowA, e2, bufA, NN);
    k_gemm_bias_relu<54, 108><<<cdiv((long long)NN * 108, B), B, 0, stream>>>(bufA, W3, b3, out, NN);
}

// Round 5
// 843.171 us; speedup vs baseline: 2.1460x; 1.2687x over previous
//
#include <hip/hip_runtime.h>

#define NN 100000
#define NE 3200000
#define SCAN_CHUNK 256

static inline int cdiv(long long a, int b) { return (int)((a + b - 1) / b); }

typedef unsigned long long ull;

// packed[i] = 0
__global__ void k_init(ull* packed, int n) {
    int i = blockIdx.x * blockDim.x + threadIdx.x;
    if (i < n) packed[i] = 0ULL;
}

// one 64-bit atomic per edge: count in bits [40..63], Q.32 fixed-point w-sum in [0..39].
// returned old count field = this edge's rank within its dst node.
__global__ void k_deg_hist(const int* __restrict__ dst, const float* __restrict__ w,
                           ull* packed, unsigned short* __restrict__ rank, int E) {
    int e = blockIdx.x * blockDim.x + threadIdx.x;
    if (e < E) {
        int d = dst[e];
        ull inc = (1ULL << 40) | (ull)((double)w[e] * 4294967296.0);
        ull old = atomicAdd(&packed[d], inc);
        rank[e] = (unsigned short)(old >> 40);
    }
}

// dis[i] = rsqrt(1 + w-sum); cnt[i] = count
__global__ void k_finish(const ull* __restrict__ packed, float* __restrict__ dis,
                         int* __restrict__ cnt, int n) {
    int i = blockIdx.x * blockDim.x + threadIdx.x;
    if (i < n) {
        ull p = packed[i];
        float deg = 1.0f + (float)((double)(p & ((1ULL << 40) - 1)) * (1.0 / 4294967296.0));
        dis[i] = rsqrtf(deg);
        cnt[i] = (int)(p >> 40);
    }
}

// per-chunk sums of cnt
__global__ void k_scan1(const int* __restrict__ cnt, int* part, int n) {
    __shared__ int s[SCAN_CHUNK];
    int t = threadIdx.x;
    int i = blockIdx.x * SCAN_CHUNK + t;
    s[t] = (i < n) ? cnt[i] : 0;
    __syncthreads();
    for (int d = SCAN_CHUNK / 2; d > 0; d >>= 1) {
        if (t < d) s[t] += s[t + d];
        __syncthreads();
    }
    if (t == 0) part[blockIdx.x] = s[0];
}

// exclusive scan of partials (nblk <= 512), in place
__global__ void k_scan2(int* part, int nblk) {
    __shared__ int s[512];
    int t = threadIdx.x;
    int v = (t < nblk) ? part[t] : 0;
    s[t] = v;
    __syncthreads();
    for (int d = 1; d < 512; d <<= 1) {
        int add = (t >= d) ? s[t - d] : 0;
        __syncthreads();
        s[t] += add;
        __syncthreads();
    }
    if (t < nblk) part[t] = s[t] - v;  // exclusive
}

// exclusive scan within chunk + chunk offset -> rowptr
__global__ void k_scan3(const int* __restrict__ cnt, const int* __restrict__ part,
                        int* rowptr, int n) {
    __shared__ int s[SCAN_CHUNK];
    int t = threadIdx.x;
    int i = blockIdx.x * SCAN_CHUNK + t;
    int v = (i < n) ? cnt[i] : 0;
    s[t] = v;
    __syncthreads();
    for (int d = 1; d < SCAN_CHUNK; d <<= 1) {
        int add = (t >= d) ? s[t - d] : 0;
        __syncthreads();
        s[t] += add;
        __syncthreads();
    }
    if (i < n) {
        int val = part[blockIdx.x] + s[t] - v;  // exclusive prefix
        rowptr[i] = val;
        if (i == n - 1) rowptr[n] = val + v;  // total = NE
    }
}

// atomic-free CSR fill: pos = rowptr[dst] + rank[e]; record = (src, norm)
__global__ void k_build(const int* __restrict__ src, const int* __restrict__ dst,
                        const float* __restrict__ w, const float* __restrict__ dis,
                        const unsigned short* __restrict__ rank,
                        const int* __restrict__ rowptr, int2* __restrict__ e2, int E) {
    int e = blockIdx.x * blockDim.x + threadIdx.x;
    if (e >= E) return;
    int s = src[e];
    int d = dst[e];
    int pos = rowptr[d] + (int)rank[e];
    float nrm = dis[s] * w[e] * dis[d];
    e2[pos] = make_int2(s, __float_as_int(nrm));
}

// gather-aggregate: thread (i,f): acc = x[i][f]*dis[i]^2 + sum_e x[src_e][f]*norm_e
template <int F>
__global__ void k_agg(const float* __restrict__ xin, const float* __restrict__ dis,
                      const int* __restrict__ rowptr, const int2* __restrict__ e2,
                      float* __restrict__ agg, int n) {
    int t = blockIdx.x * blockDim.x + threadIdx.x;
    if (t >= n * F) return;
    int i = t / F;
    int f = t - i * F;
    float d = dis[i];
    float acc = xin[i * F + f] * d * d;
    int e0 = rowptr[i];
    int e1 = rowptr[i + 1];
    for (int e = e0; e < e1; ++e) {
        int2 p = e2[e];
        acc = fmaf(xin[p.x * F + f], __int_as_float(p.y), acc);
    }
    agg[t] = acc;
}

// out[i][o] = relu(sum_f agg[i][f] * W[f][o] + b[o])
template <int FIN, int FOUT>
__global__ void k_gemm_bias_relu(const float* __restrict__ agg, const float* __restrict__ W,
                                 const float* __restrict__ b, float* __restrict__ out, int n) {
    __shared__ float Ws[FIN * FOUT];
    __shared__ float bs[FOUT];
    for (int t = threadIdx.x; t < FIN * FOUT; t += blockDim.x) Ws[t] = W[t];
    for (int t = threadIdx.x; t < FOUT; t += blockDim.x) bs[t] = b[t];
    __syncthreads();
    int t = blockIdx.x * blockDim.x + threadIdx.x;
    if (t < n * FOUT) {
        int i = t / FOUT;
        int o = t - i * FOUT;
        float acc = bs[o];
        const float* row = agg + i * FIN;
#pragma unroll
        for (int f = 0; f < FIN; ++f) acc = fmaf(row[f], Ws[f * FOUT + o], acc);
        out[t] = fmaxf(acc, 0.0f);
    }
}

extern "C" void kernel_launch(void* const* d_in, const int* in_sizes, int n_in,
                              void* d_out, int out_size, void* d_ws, size_t ws_size,
                              hipStream_t stream) {
    const float* x  = (const float*)d_in[0];
    const int*   ei = (const int*)d_in[1];  // [2][NE]: row0=src, row1=dst
    const float* ew = (const float*)d_in[2];
    const float* W1 = (const float*)d_in[3];
    const float* b1 = (const float*)d_in[4];
    const float* W2 = (const float*)d_in[5];
    const float* b2 = (const float*)d_in[6];
    const float* W3 = (const float*)d_in[7];
    const float* b3 = (const float*)d_in[8];
    float* out = (float*)d_out;

    const int* src = ei;
    const int* dst = ei + NE;

    // workspace layout (512B aligned chunks)
    char* ws = (char*)d_ws;
    size_t off = 0;
    auto alloc = [&](size_t bytes) {
        char* p = ws + off;
        off += (bytes + 511) / 512 * 512;
        return p;
    };
    float* dis    = (float*)alloc((size_t)NN * 4);
    int*   rowptr = (int*)alloc((size_t)(NN + 1) * 4);
    int*   part   = (int*)alloc(512 * 4);
    int2*  e2     = (int2*)alloc((size_t)NE * 8);
    float* bufA   = (float*)alloc((size_t)NN * 54 * 4);
    float* bufB   = (float*)alloc((size_t)NN * 54 * 4);

    // aliases into buf regions (all dead before aggs/gemms start writing bufs):
    unsigned short* rank = (unsigned short*)bufA;  // 6.4MB, dead after k_build
    ull* packed = (ull*)bufB;                      // 0.8MB, dead after k_finish
    int* cnt    = (int*)((char*)bufB + (size_t)NN * 8);  // 0.4MB, dead after k_scan3

    const int B = 256;
    const int NBLK = cdiv(NN, SCAN_CHUNK);  // 391

    // ---- norm + CSR build ----
    k_init<<<cdiv(NN, B), B, 0, stream>>>(packed, NN);
    k_deg_hist<<<cdiv(NE, B), B, 0, stream>>>(dst, ew, packed, rank, NE);
    k_finish<<<cdiv(NN, B), B, 0, stream>>>(packed, dis, cnt, NN);
    k_scan1<<<NBLK, SCAN_CHUNK, 0, stream>>>(cnt, part, NN);
    k_scan2<<<1, 512, 0, stream>>>(part, NBLK);
    k_scan3<<<NBLK, SCAN_CHUNK, 0, stream>>>(cnt, part, rowptr, NN);
    k_build<<<cdiv(NE, B), B, 0, stream>>>(src, dst, ew, dis, rank, rowptr, e2, NE);

    // ---- layer 1: agg(x, F=9) -> gemm 9x18 -> bufB ----
    k_agg<9><<<cdiv((long long)NN * 9, B), B, 0, stream>>>(x, dis, rowptr, e2, bufA, NN);
    k_gemm_bias_relu<9, 18><<<cdiv((long long)NN * 18, B), B, 0, stream>>>(bufA, W1, b1, bufB, NN);

    // ---- layer 2: agg(bufB, F=18) -> gemm 18x54 -> bufB ----
    k_agg<18><<<cdiv((long long)NN * 18, B), B, 0, stream>>>(bufB, dis, rowptr, e2, bufA, NN);
    k_gemm_bias_relu<18, 54><<<cdiv((long long)NN * 54, B), B, 0, stream>>>(bufA, W2, b2, bufB, NN);

    // ---- layer 3: agg(bufB, F=54) -> gemm 54x108 -> d_out ----
    k_agg<54><<<cdiv((long long)NN * 54, B), B, 0, stream>>>(bufB, dis, rowptr, e2, bufA, NN);
    k_gemm_bias_relu<54, 108><<<cdiv((long long)NN * 108, B), B, 0, stream>>>(bufA, W3, b3, out, NN);
}

// Round 6
// 641.386 us; speedup vs baseline: 2.8212x; 1.3146x over previous
//
#include <hip/hip_runtime.h>

#define NN 100000
#define NE 3200000
#define SCAN_CHUNK 256

static inline int cdiv(long long a, int b) { return (int)((a + b - 1) / b); }

typedef unsigned long long ull;

// packed[i] = 0
__global__ void k_init(ull* packed, int n) {
    int i = blockIdx.x * blockDim.x + threadIdx.x;
    if (i < n) packed[i] = 0ULL;
}

// one 64-bit atomic per edge: count in bits [40..63], Q.32 fixed-point w-sum in [0..39].
// returned old count field = this edge's rank within its dst node.
__global__ void k_deg_hist(const int* __restrict__ dst, const float* __restrict__ w,
                           ull* packed, unsigned short* __restrict__ rank, int E) {
    int e = blockIdx.x * blockDim.x + threadIdx.x;
    if (e < E) {
        int d = dst[e];
        ull inc = (1ULL << 40) | (ull)((double)w[e] * 4294967296.0);
        ull old = atomicAdd(&packed[d], inc);
        rank[e] = (unsigned short)(old >> 40);
    }
}

// dis[i] = rsqrt(1 + w-sum); cnt[i] = count
__global__ void k_finish(const ull* __restrict__ packed, float* __restrict__ dis,
                         int* __restrict__ cnt, int n) {
    int i = blockIdx.x * blockDim.x + threadIdx.x;
    if (i < n) {
        ull p = packed[i];
        float deg = 1.0f + (float)((double)(p & ((1ULL << 40) - 1)) * (1.0 / 4294967296.0));
        dis[i] = rsqrtf(deg);
        cnt[i] = (int)(p >> 40);
    }
}

// per-chunk sums of cnt
__global__ void k_scan1(const int* __restrict__ cnt, int* part, int n) {
    __shared__ int s[SCAN_CHUNK];
    int t = threadIdx.x;
    int i = blockIdx.x * SCAN_CHUNK + t;
    s[t] = (i < n) ? cnt[i] : 0;
    __syncthreads();
    for (int d = SCAN_CHUNK / 2; d > 0; d >>= 1) {
        if (t < d) s[t] += s[t + d];
        __syncthreads();
    }
    if (t == 0) part[blockIdx.x] = s[0];
}

// exclusive scan of partials (nblk <= 512), in place
__global__ void k_scan2(int* part, int nblk) {
    __shared__ int s[512];
    int t = threadIdx.x;
    int v = (t < nblk) ? part[t] : 0;
    s[t] = v;
    __syncthreads();
    for (int d = 1; d < 512; d <<= 1) {
        int add = (t >= d) ? s[t - d] : 0;
        __syncthreads();
        s[t] += add;
        __syncthreads();
    }
    if (t < nblk) part[t] = s[t] - v;  // exclusive
}

// exclusive scan within chunk + chunk offset -> rowptr
__global__ void k_scan3(const int* __restrict__ cnt, const int* __restrict__ part,
                        int* rowptr, int n) {
    __shared__ int s[SCAN_CHUNK];
    int t = threadIdx.x;
    int i = blockIdx.x * SCAN_CHUNK + t;
    int v = (i < n) ? cnt[i] : 0;
    s[t] = v;
    __syncthreads();
    for (int d = 1; d < SCAN_CHUNK; d <<= 1) {
        int add = (t >= d) ? s[t - d] : 0;
        __syncthreads();
        s[t] += add;
        __syncthreads();
    }
    if (i < n) {
        int val = part[blockIdx.x] + s[t] - v;  // exclusive prefix
        rowptr[i] = val;
        if (i == n - 1) rowptr[n] = val + v;  // total = NE
    }
}

// atomic-free CSR fill: pos = rowptr[dst] + rank[e]; record = (src, norm)
__global__ void k_build(const int* __restrict__ src, const int* __restrict__ dst,
                        const float* __restrict__ w, const float* __restrict__ dis,
                        const unsigned short* __restrict__ rank,
                        const int* __restrict__ rowptr, int2* __restrict__ e2, int E) {
    int e = blockIdx.x * blockDim.x + threadIdx.x;
    if (e >= E) return;
    int s = src[e];
    int d = dst[e];
    int pos = rowptr[d] + (int)rank[e];
    float nrm = dis[s] * w[e] * dis[d];
    e2[pos] = make_int2(s, __float_as_int(nrm));
}

// gather-aggregate, node-aligned waves + unroll-4 edge loop for MLP.
// F = feature dim, FPL = floats per lane (1 or 2).
// LPN = F/FPL lanes per node; NPW = 64/LPN nodes per wave; 4 waves/block.
template <int F, int FPL>
__global__ void k_agg2(const float* __restrict__ xin, const float* __restrict__ dis,
                       const int* __restrict__ rowptr, const int2* __restrict__ e2,
                       float* __restrict__ agg, int n) {
    constexpr int LPN = F / FPL;
    constexpr int NPW = 64 / LPN;
    constexpr int NPB = NPW * 4;
    int w = threadIdx.x >> 6;
    int l = threadIdx.x & 63;
    int ni = l / LPN;
    int sub = l - ni * LPN;
    if (ni >= NPW) return;
    int i = (blockIdx.x * 4 + w) * NPW + ni;
    if (i >= n) return;

    float d = dis[i];
    float dd = d * d;
    const float* xrow = xin + (size_t)i * F + sub * FPL;
    float acc0 = xrow[0] * dd;
    float acc1 = (FPL == 2) ? xrow[1] * dd : 0.0f;

    int e0 = rowptr[i];
    int e1 = rowptr[i + 1];
    int e = e0;
    for (; e + 4 <= e1; e += 4) {
        int2 p0 = e2[e + 0];
        int2 p1 = e2[e + 1];
        int2 p2 = e2[e + 2];
        int2 p3 = e2[e + 3];
        if (FPL == 2) {
            float2 v0 = *(const float2*)(xin + (size_t)p0.x * F + sub * 2);
            float2 v1 = *(const float2*)(xin + (size_t)p1.x * F + sub * 2);
            float2 v2 = *(const float2*)(xin + (size_t)p2.x * F + sub * 2);
            float2 v3 = *(const float2*)(xin + (size_t)p3.x * F + sub * 2);
            acc0 = fmaf(v0.x, __int_as_float(p0.y), acc0);
            acc1 = fmaf(v0.y, __int_as_float(p0.y), acc1);
            acc0 = fmaf(v1.x, __int_as_float(p1.y), acc0);
            acc1 = fmaf(v1.y, __int_as_float(p1.y), acc1);
            acc0 = fmaf(v2.x, __int_as_float(p2.y), acc0);
            acc1 = fmaf(v2.y, __int_as_float(p2.y), acc1);
            acc0 = fmaf(v3.x, __int_as_float(p3.y), acc0);
            acc1 = fmaf(v3.y, __int_as_float(p3.y), acc1);
        } else {
            float v0 = xin[(size_t)p0.x * F + sub];
            float v1 = xin[(size_t)p1.x * F + sub];
            float v2 = xin[(size_t)p2.x * F + sub];
            float v3 = xin[(size_t)p3.x * F + sub];
            acc0 = fmaf(v0, __int_as_float(p0.y), acc0);
            acc0 = fmaf(v1, __int_as_float(p1.y), acc0);
            acc0 = fmaf(v2, __int_as_float(p2.y), acc0);
            acc0 = fmaf(v3, __int_as_float(p3.y), acc0);
        }
    }
    for (; e < e1; ++e) {
        int2 p = e2[e];
        if (FPL == 2) {
            float2 v = *(const float2*)(xin + (size_t)p.x * F + sub * 2);
            acc0 = fmaf(v.x, __int_as_float(p.y), acc0);
            acc1 = fmaf(v.y, __int_as_float(p.y), acc1);
        } else {
            acc0 = fmaf(xin[(size_t)p.x * F + sub], __int_as_float(p.y), acc0);
        }
    }

    float* orow = agg + (size_t)i * F + sub * FPL;
    if (FPL == 2) {
        *(float2*)orow = make_float2(acc0, acc1);
    } else {
        orow[0] = acc0;
    }
}

// out[i][o] = relu(sum_f agg[i][f] * W[f][o] + b[o])
template <int FIN, int FOUT>
__global__ void k_gemm_bias_relu(const float* __restrict__ agg, const float* __restrict__ W,
                                 const float* __restrict__ b, float* __restrict__ out, int n) {
    __shared__ float Ws[FIN * FOUT];
    __shared__ float bs[FOUT];
    for (int t = threadIdx.x; t < FIN * FOUT; t += blockDim.x) Ws[t] = W[t];
    for (int t = threadIdx.x; t < FOUT; t += blockDim.x) bs[t] = b[t];
    __syncthreads();
    int t = blockIdx.x * blockDim.x + threadIdx.x;
    if (t < n * FOUT) {
        int i = t / FOUT;
        int o = t - i * FOUT;
        float acc = bs[o];
        const float* row = agg + i * FIN;
#pragma unroll
        for (int f = 0; f < FIN; ++f) acc = fmaf(row[f], Ws[f * FOUT + o], acc);
        out[t] = fmaxf(acc, 0.0f);
    }
}

extern "C" void kernel_launch(void* const* d_in, const int* in_sizes, int n_in,
                              void* d_out, int out_size, void* d_ws, size_t ws_size,
                              hipStream_t stream) {
    const float* x  = (const float*)d_in[0];
    const int*   ei = (const int*)d_in[1];  // [2][NE]: row0=src, row1=dst
    const float* ew = (const float*)d_in[2];
    const float* W1 = (const float*)d_in[3];
    const float* b1 = (const float*)d_in[4];
    const float* W2 = (const float*)d_in[5];
    const float* b2 = (const float*)d_in[6];
    const float* W3 = (const float*)d_in[7];
    const float* b3 = (const float*)d_in[8];
    float* out = (float*)d_out;

    const int* src = ei;
    const int* dst = ei + NE;

    // workspace layout (512B aligned chunks)
    char* ws = (char*)d_ws;
    size_t off = 0;
    auto alloc = [&](size_t bytes) {
        char* p = ws + off;
        off += (bytes + 511) / 512 * 512;
        return p;
    };
    float* dis    = (float*)alloc((size_t)NN * 4);
    int*   rowptr = (int*)alloc((size_t)(NN + 1) * 4);
    int*   part   = (int*)alloc(512 * 4);
    int2*  e2     = (int2*)alloc((size_t)NE * 8);
    float* bufA   = (float*)alloc((size_t)NN * 54 * 4);
    float* bufB   = (float*)alloc((size_t)NN * 54 * 4);

    // aliases into buf regions (all dead before aggs/gemms start writing bufs):
    unsigned short* rank = (unsigned short*)bufA;  // 6.4MB, dead after k_build
    ull* packed = (ull*)bufB;                      // 0.8MB, dead after k_finish
    int* cnt    = (int*)((char*)bufB + (size_t)NN * 8);  // 0.4MB, dead after k_scan3

    const int B = 256;
    const int NBLK = cdiv(NN, SCAN_CHUNK);  // 391

    // ---- norm + CSR build ----
    k_init<<<cdiv(NN, B), B, 0, stream>>>(packed, NN);
    k_deg_hist<<<cdiv(NE, B), B, 0, stream>>>(dst, ew, packed, rank, NE);
    k_finish<<<cdiv(NN, B), B, 0, stream>>>(packed, dis, cnt, NN);
    k_scan1<<<NBLK, SCAN_CHUNK, 0, stream>>>(cnt, part, NN);
    k_scan2<<<1, 512, 0, stream>>>(part, NBLK);
    k_scan3<<<NBLK, SCAN_CHUNK, 0, stream>>>(cnt, part, rowptr, NN);
    k_build<<<cdiv(NE, B), B, 0, stream>>>(src, dst, ew, dis, rank, rowptr, e2, NE);

    // nodes per block for each agg config
    const int NPB9  = (64 / (9 / 1)) * 4;   // 28
    const int NPB18 = (64 / (18 / 2)) * 4;  // 28
    const int NPB54 = (64 / (54 / 2)) * 4;  // 8

    // ---- layer 1: agg(x, F=9) -> gemm 9x18 -> bufB ----
    k_agg2<9, 1><<<cdiv(NN, NPB9), B, 0, stream>>>(x, dis, rowptr, e2, bufA, NN);
    k_gemm_bias_relu<9, 18><<<cdiv((long long)NN * 18, B), B, 0, stream>>>(bufA, W1, b1, bufB, NN);

    // ---- layer 2: agg(bufB, F=18) -> gemm 18x54 -> bufB ----
    k_agg2<18, 2><<<cdiv(NN, NPB18), B, 0, stream>>>(bufB, dis, rowptr, e2, bufA, NN);
    k_gemm_bias_relu<18, 54><<<cdiv((long long)NN * 54, B), B, 0, stream>>>(bufA, W2, b2, bufB, NN);

    // ---- layer 3: agg(bufB, F=54) -> gemm 54x108 -> d_out ----
    k_agg2<54, 2><<<cdiv(NN, NPB54), B, 0, stream>>>(bufB, dis, rowptr, e2, bufA, NN);
    k_gemm_bias_relu<54, 108><<<cdiv((long long)NN * 108, B), B, 0, stream>>>(bufA, W3, b3, out, NN);
}

// Round 7
// 552.879 us; speedup vs baseline: 3.2728x; 1.1601x over previous
//
#include <hip/hip_runtime.h>

#define NN 100000
#define NE 3200000
#define SCAN_CHUNK 256

static inline int cdiv(long long a, int b) { return (int)((a + b - 1) / b); }

typedef unsigned long long ull;

// packed[i] = 0
__global__ void k_init(ull* packed, int n) {
    int i = blockIdx.x * blockDim.x + threadIdx.x;
    if (i < n) packed[i] = 0ULL;
}

// one 64-bit atomic per edge: count in bits [40..63], Q.32 fixed-point w-sum in [0..39].
// returned old count field = this edge's rank within its dst node.
__global__ void k_deg_hist(const int* __restrict__ dst, const float* __restrict__ w,
                           ull* packed, unsigned short* __restrict__ rank, int E) {
    int e = blockIdx.x * blockDim.x + threadIdx.x;
    if (e < E) {
        int d = dst[e];
        ull inc = (1ULL << 40) | (ull)((double)w[e] * 4294967296.0);
        ull old = atomicAdd(&packed[d], inc);
        rank[e] = (unsigned short)(old >> 40);
    }
}

// dis[i] = rsqrt(1 + w-sum); cnt[i] = count
__global__ void k_finish(const ull* __restrict__ packed, float* __restrict__ dis,
                         int* __restrict__ cnt, int n) {
    int i = blockIdx.x * blockDim.x + threadIdx.x;
    if (i < n) {
        ull p = packed[i];
        float deg = 1.0f + (float)((double)(p & ((1ULL << 40) - 1)) * (1.0 / 4294967296.0));
        dis[i] = rsqrtf(deg);
        cnt[i] = (int)(p >> 40);
    }
}

// per-chunk sums of cnt
__global__ void k_scan1(const int* __restrict__ cnt, int* part, int n) {
    __shared__ int s[SCAN_CHUNK];
    int t = threadIdx.x;
    int i = blockIdx.x * SCAN_CHUNK + t;
    s[t] = (i < n) ? cnt[i] : 0;
    __syncthreads();
    for (int d = SCAN_CHUNK / 2; d > 0; d >>= 1) {
        if (t < d) s[t] += s[t + d];
        __syncthreads();
    }
    if (t == 0) part[blockIdx.x] = s[0];
}

// exclusive scan of partials (nblk <= 512), in place
__global__ void k_scan2(int* part, int nblk) {
    __shared__ int s[512];
    int t = threadIdx.x;
    int v = (t < nblk) ? part[t] : 0;
    s[t] = v;
    __syncthreads();
    for (int d = 1; d < 512; d <<= 1) {
        int add = (t >= d) ? s[t - d] : 0;
        __syncthreads();
        s[t] += add;
        __syncthreads();
    }
    if (t < nblk) part[t] = s[t] - v;  // exclusive
}

// exclusive scan within chunk + chunk offset -> rowptr
__global__ void k_scan3(const int* __restrict__ cnt, const int* __restrict__ part,
                        int* rowptr, int n) {
    __shared__ int s[SCAN_CHUNK];
    int t = threadIdx.x;
    int i = blockIdx.x * SCAN_CHUNK + t;
    int v = (i < n) ? cnt[i] : 0;
    s[t] = v;
    __syncthreads();
    for (int d = 1; d < SCAN_CHUNK; d <<= 1) {
        int add = (t >= d) ? s[t - d] : 0;
        __syncthreads();
        s[t] += add;
        __syncthreads();
    }
    if (i < n) {
        int val = part[blockIdx.x] + s[t] - v;  // exclusive prefix
        rowptr[i] = val;
        if (i == n - 1) rowptr[n] = val + v;  // total = NE
    }
}

// atomic-free CSR fill: pos = rowptr[dst] + rank[e]; record = (src, norm)
__global__ void k_build(const int* __restrict__ src, const int* __restrict__ dst,
                        const float* __restrict__ w, const float* __restrict__ dis,
                        const unsigned short* __restrict__ rank,
                        const int* __restrict__ rowptr, int2* __restrict__ e2, int E) {
    int e = blockIdx.x * blockDim.x + threadIdx.x;
    if (e >= E) return;
    int s = src[e];
    int d = dst[e];
    int pos = rowptr[d] + (int)rank[e];
    float nrm = dis[s] * w[e] * dis[d];
    e2[pos] = make_int2(s, __float_as_int(nrm));
}

// gather-aggregate, node-aligned waves + unroll-4 edge loop for MLP.
// F = feature dim, FPL = floats per lane (1 or 2).
// LPN = F/FPL lanes per node; NPW = 64/LPN nodes per wave; 4 waves/block.
template <int F, int FPL>
__global__ void k_agg2(const float* __restrict__ xin, const float* __restrict__ dis,
                       const int* __restrict__ rowptr, const int2* __restrict__ e2,
                       float* __restrict__ agg, int n) {
    constexpr int LPN = F / FPL;
    constexpr int NPW = 64 / LPN;
    int w = threadIdx.x >> 6;
    int l = threadIdx.x & 63;
    int ni = l / LPN;
    int sub = l - ni * LPN;
    if (ni >= NPW) return;
    int i = (blockIdx.x * 4 + w) * NPW + ni;
    if (i >= n) return;

    float d = dis[i];
    float dd = d * d;
    const float* xrow = xin + (size_t)i * F + sub * FPL;
    float acc0 = xrow[0] * dd;
    float acc1 = (FPL == 2) ? xrow[1] * dd : 0.0f;

    int e0 = rowptr[i];
    int e1 = rowptr[i + 1];
    int e = e0;
    for (; e + 4 <= e1; e += 4) {
        int2 p0 = e2[e + 0];
        int2 p1 = e2[e + 1];
        int2 p2 = e2[e + 2];
        int2 p3 = e2[e + 3];
        if (FPL == 2) {
            float2 v0 = *(const float2*)(xin + (size_t)p0.x * F + sub * 2);
            float2 v1 = *(const float2*)(xin + (size_t)p1.x * F + sub * 2);
            float2 v2 = *(const float2*)(xin + (size_t)p2.x * F + sub * 2);
            float2 v3 = *(const float2*)(xin + (size_t)p3.x * F + sub * 2);
            acc0 = fmaf(v0.x, __int_as_float(p0.y), acc0);
            acc1 = fmaf(v0.y, __int_as_float(p0.y), acc1);
            acc0 = fmaf(v1.x, __int_as_float(p1.y), acc0);
            acc1 = fmaf(v1.y, __int_as_float(p1.y), acc1);
            acc0 = fmaf(v2.x, __int_as_float(p2.y), acc0);
            acc1 = fmaf(v2.y, __int_as_float(p2.y), acc1);
            acc0 = fmaf(v3.x, __int_as_float(p3.y), acc0);
            acc1 = fmaf(v3.y, __int_as_float(p3.y), acc1);
        } else {
            float v0 = xin[(size_t)p0.x * F + sub];
            float v1 = xin[(size_t)p1.x * F + sub];
            float v2 = xin[(size_t)p2.x * F + sub];
            float v3 = xin[(size_t)p3.x * F + sub];
            acc0 = fmaf(v0, __int_as_float(p0.y), acc0);
            acc0 = fmaf(v1, __int_as_float(p1.y), acc0);
            acc0 = fmaf(v2, __int_as_float(p2.y), acc0);
            acc0 = fmaf(v3, __int_as_float(p3.y), acc0);
        }
    }
    for (; e < e1; ++e) {
        int2 p = e2[e];
        if (FPL == 2) {
            float2 v = *(const float2*)(xin + (size_t)p.x * F + sub * 2);
            acc0 = fmaf(v.x, __int_as_float(p.y), acc0);
            acc1 = fmaf(v.y, __int_as_float(p.y), acc1);
        } else {
            acc0 = fmaf(xin[(size_t)p.x * F + sub], __int_as_float(p.y), acc0);
        }
    }

    float* orow = agg + (size_t)i * F + sub * FPL;
    if (FPL == 2) {
        *(float2*)orow = make_float2(acc0, acc1);
    } else {
        orow[0] = acc0;
    }
}

// register-tiled GEMM: one thread per node. row[FIN] in VGPRs; W/b accesses are
// wave-uniform -> scalar loads (SGPR pipe), no LDS. TN outputs per o-chunk.
template <int FIN, int FOUT, int TN>
__global__ void k_gemm2(const float* __restrict__ agg, const float* __restrict__ W,
                        const float* __restrict__ b, float* __restrict__ out, int n) {
    int i = blockIdx.x * blockDim.x + threadIdx.x;
    if (i >= n) return;
    float row[FIN];
    const float* arow = agg + (size_t)i * FIN;
#pragma unroll
    for (int f = 0; f < FIN; ++f) row[f] = arow[f];
    float* orow = out + (size_t)i * FOUT;
#pragma unroll 1
    for (int oc = 0; oc < FOUT; oc += TN) {
        float acc[TN];
#pragma unroll
        for (int j = 0; j < TN; ++j) acc[j] = b[oc + j];
#pragma unroll
        for (int f = 0; f < FIN; ++f) {
#pragma unroll
            for (int j = 0; j < TN; ++j)
                acc[j] = fmaf(row[f], W[f * FOUT + oc + j], acc[j]);
        }
#pragma unroll
        for (int j = 0; j < TN; ++j) orow[oc + j] = fmaxf(acc[j], 0.0f);
    }
}

extern "C" void kernel_launch(void* const* d_in, const int* in_sizes, int n_in,
                              void* d_out, int out_size, void* d_ws, size_t ws_size,
                              hipStream_t stream) {
    const float* x  = (const float*)d_in[0];
    const int*   ei = (const int*)d_in[1];  // [2][NE]: row0=src, row1=dst
    const float* ew = (const float*)d_in[2];
    const float* W1 = (const float*)d_in[3];
    const float* b1 = (const float*)d_in[4];
    const float* W2 = (const float*)d_in[5];
    const float* b2 = (const float*)d_in[6];
    const float* W3 = (const float*)d_in[7];
    const float* b3 = (const float*)d_in[8];
    float* out = (float*)d_out;

    const int* src = ei;
    const int* dst = ei + NE;

    // workspace layout (512B aligned chunks)
    char* ws = (char*)d_ws;
    size_t off = 0;
    auto alloc = [&](size_t bytes) {
        char* p = ws + off;
        off += (bytes + 511) / 512 * 512;
        return p;
    };
    float* dis    = (float*)alloc((size_t)NN * 4);
    int*   rowptr = (int*)alloc((size_t)(NN + 1) * 4);
    int*   part   = (int*)alloc(512 * 4);
    int2*  e2     = (int2*)alloc((size_t)NE * 8);
    float* bufA   = (float*)alloc((size_t)NN * 54 * 4);
    float* bufB   = (float*)alloc((size_t)NN * 54 * 4);

    // aliases into buf regions (all dead before aggs/gemms start writing bufs):
    unsigned short* rank = (unsigned short*)bufA;  // 6.4MB, dead after k_build
    ull* packed = (ull*)bufB;                      // 0.8MB, dead after k_finish
    int* cnt    = (int*)((char*)bufB + (size_t)NN * 8);  // 0.4MB, dead after k_scan3

    const int B = 256;
    const int NBLK = cdiv(NN, SCAN_CHUNK);  // 391

    // ---- norm + CSR build ----
    k_init<<<cdiv(NN, B), B, 0, stream>>>(packed, NN);
    k_deg_hist<<<cdiv(NE, B), B, 0, stream>>>(dst, ew, packed, rank, NE);
    k_finish<<<cdiv(NN, B), B, 0, stream>>>(packed, dis, cnt, NN);
    k_scan1<<<NBLK, SCAN_CHUNK, 0, stream>>>(cnt, part, NN);
    k_scan2<<<1, 512, 0, stream>>>(part, NBLK);
    k_scan3<<<NBLK, SCAN_CHUNK, 0, stream>>>(cnt, part, rowptr, NN);
    k_build<<<cdiv(NE, B), B, 0, stream>>>(src, dst, ew, dis, rank, rowptr, e2, NE);

    // nodes per block for each agg config
    const int NPB9  = (64 / (9 / 1)) * 4;   // 28
    const int NPB18 = (64 / (18 / 2)) * 4;  // 28
    const int NPB54 = (64 / (54 / 2)) * 4;  // 8

    // ---- layer 1: agg(x, F=9) -> gemm 9x18 -> bufB ----
    k_agg2<9, 1><<<cdiv(NN, NPB9), B, 0, stream>>>(x, dis, rowptr, e2, bufA, NN);
    k_gemm2<9, 18, 6><<<cdiv(NN, B), B, 0, stream>>>(bufA, W1, b1, bufB, NN);

    // ---- layer 2: agg(bufB, F=18) -> gemm 18x54 -> bufB ----
    k_agg2<18, 2><<<cdiv(NN, NPB18), B, 0, stream>>>(bufB, dis, rowptr, e2, bufA, NN);
    k_gemm2<18, 54, 6><<<cdiv(NN, B), B, 0, stream>>>(bufA, W2, b2, bufB, NN);

    // ---- layer 3: agg(bufB, F=54) -> gemm 54x108 -> d_out ----
    k_agg2<54, 2><<<cdiv(NN, NPB54), B, 0, stream>>>(bufB, dis, rowptr, e2, bufA, NN);
    k_gemm2<54, 108, 6><<<cdiv(NN, B), B, 0, stream>>>(bufA, W3, b3, out, NN);
}

// Round 8
// 551.545 us; speedup vs baseline: 3.2808x; 1.0024x over previous
//
#include <hip/hip_runtime.h>

#define NN 100000
#define NE 3200000
#define SCAN_CHUNK 256
#define PSTRIDE 8  // packed[] element stride (u64s): one node per 64B line

static inline int cdiv(long long a, int b) { return (int)((a + b - 1) / b); }

typedef unsigned long long ull;

// packed[i] = 0 (zero the whole padded table)
__global__ void k_init(ull* packed, int n8) {
    int i = blockIdx.x * blockDim.x + threadIdx.x;
    if (i < n8) packed[i] = 0ULL;
}

// one 64-bit atomic per edge: count in bits [40..63], Q.32 fixed-point w-sum in [0..39].
// packed table is 64B-strided: one node per cacheline to kill line contention.
// returned old count field = this edge's rank within its dst node.
__global__ void k_deg_hist(const int* __restrict__ dst, const float* __restrict__ w,
                           ull* packed, unsigned short* __restrict__ rank, int E) {
    int e = blockIdx.x * blockDim.x + threadIdx.x;
    if (e < E) {
        int d = dst[e];
        ull inc = (1ULL << 40) | (ull)((double)w[e] * 4294967296.0);
        ull old = atomicAdd(&packed[(size_t)d * PSTRIDE], inc);
        rank[e] = (unsigned short)(old >> 40);
    }
}

// dis[i] = rsqrt(1 + w-sum); cnt[i] = count
__global__ void k_finish(const ull* __restrict__ packed, float* __restrict__ dis,
                         int* __restrict__ cnt, int n) {
    int i = blockIdx.x * blockDim.x + threadIdx.x;
    if (i < n) {
        ull p = packed[(size_t)i * PSTRIDE];
        float deg = 1.0f + (float)((double)(p & ((1ULL << 40) - 1)) * (1.0 / 4294967296.0));
        dis[i] = rsqrtf(deg);
        cnt[i] = (int)(p >> 40);
    }
}

// per-chunk sums of cnt
__global__ void k_scan1(const int* __restrict__ cnt, int* part, int n) {
    __shared__ int s[SCAN_CHUNK];
    int t = threadIdx.x;
    int i = blockIdx.x * SCAN_CHUNK + t;
    s[t] = (i < n) ? cnt[i] : 0;
    __syncthreads();
    for (int d = SCAN_CHUNK / 2; d > 0; d >>= 1) {
        if (t < d) s[t] += s[t + d];
        __syncthreads();
    }
    if (t == 0) part[blockIdx.x] = s[0];
}

// exclusive scan of partials (nblk <= 512), in place
__global__ void k_scan2(int* part, int nblk) {
    __shared__ int s[512];
    int t = threadIdx.x;
    int v = (t < nblk) ? part[t] : 0;
    s[t] = v;
    __syncthreads();
    for (int d = 1; d < 512; d <<= 1) {
        int add = (t >= d) ? s[t - d] : 0;
        __syncthreads();
        s[t] += add;
        __syncthreads();
    }
    if (t < nblk) part[t] = s[t] - v;  // exclusive
}

// exclusive scan within chunk + chunk offset -> rowptr
__global__ void k_scan3(const int* __restrict__ cnt, const int* __restrict__ part,
                        int* rowptr, int n) {
    __shared__ int s[SCAN_CHUNK];
    int t = threadIdx.x;
    int i = blockIdx.x * SCAN_CHUNK + t;
    int v = (i < n) ? cnt[i] : 0;
    s[t] = v;
    __syncthreads();
    for (int d = 1; d < SCAN_CHUNK; d <<= 1) {
        int add = (t >= d) ? s[t - d] : 0;
        __syncthreads();
        s[t] += add;
        __syncthreads();
    }
    if (i < n) {
        int val = part[blockIdx.x] + s[t] - v;  // exclusive prefix
        rowptr[i] = val;
        if (i == n - 1) rowptr[n] = val + v;  // total = NE
    }
}

// atomic-free CSR fill: pos = rowptr[dst] + rank[e]; record = (src, norm)
__global__ void k_build(const int* __restrict__ src, const int* __restrict__ dst,
                        const float* __restrict__ w, const float* __restrict__ dis,
                        const unsigned short* __restrict__ rank,
                        const int* __restrict__ rowptr, int2* __restrict__ e2, int E) {
    int e = blockIdx.x * blockDim.x + threadIdx.x;
    if (e >= E) return;
    int s = src[e];
    int d = dst[e];
    int pos = rowptr[d] + (int)rank[e];
    float nrm = dis[s] * w[e] * dis[d];
    e2[pos] = make_int2(s, __float_as_int(nrm));
}

// gather-aggregate, node-aligned waves + unroll-4 edge loop for MLP.
// F = feature dim, FPL = floats per lane (1 or 2).
// LPN = F/FPL lanes per node; NPW = 64/LPN nodes per wave; 4 waves/block.
template <int F, int FPL>
__global__ void k_agg2(const float* __restrict__ xin, const float* __restrict__ dis,
                       const int* __restrict__ rowptr, const int2* __restrict__ e2,
                       float* __restrict__ agg, int n) {
    constexpr int LPN = F / FPL;
    constexpr int NPW = 64 / LPN;
    int w = threadIdx.x >> 6;
    int l = threadIdx.x & 63;
    int ni = l / LPN;
    int sub = l - ni * LPN;
    if (ni >= NPW) return;
    int i = (blockIdx.x * 4 + w) * NPW + ni;
    if (i >= n) return;

    float d = dis[i];
    float dd = d * d;
    const float* xrow = xin + (size_t)i * F + sub * FPL;
    float acc0 = xrow[0] * dd;
    float acc1 = (FPL == 2) ? xrow[1] * dd : 0.0f;

    int e0 = rowptr[i];
    int e1 = rowptr[i + 1];
    int e = e0;
    for (; e + 4 <= e1; e += 4) {
        int2 p0 = e2[e + 0];
        int2 p1 = e2[e + 1];
        int2 p2 = e2[e + 2];
        int2 p3 = e2[e + 3];
        if (FPL == 2) {
            float2 v0 = *(const float2*)(xin + (size_t)p0.x * F + sub * 2);
            float2 v1 = *(const float2*)(xin + (size_t)p1.x * F + sub * 2);
            float2 v2 = *(const float2*)(xin + (size_t)p2.x * F + sub * 2);
            float2 v3 = *(const float2*)(xin + (size_t)p3.x * F + sub * 2);
            acc0 = fmaf(v0.x, __int_as_float(p0.y), acc0);
            acc1 = fmaf(v0.y, __int_as_float(p0.y), acc1);
            acc0 = fmaf(v1.x, __int_as_float(p1.y), acc0);
            acc1 = fmaf(v1.y, __int_as_float(p1.y), acc1);
            acc0 = fmaf(v2.x, __int_as_float(p2.y), acc0);
            acc1 = fmaf(v2.y, __int_as_float(p2.y), acc1);
            acc0 = fmaf(v3.x, __int_as_float(p3.y), acc0);
            acc1 = fmaf(v3.y, __int_as_float(p3.y), acc1);
        } else {
            float v0 = xin[(size_t)p0.x * F + sub];
            float v1 = xin[(size_t)p1.x * F + sub];
            float v2 = xin[(size_t)p2.x * F + sub];
            float v3 = xin[(size_t)p3.x * F + sub];
            acc0 = fmaf(v0, __int_as_float(p0.y), acc0);
            acc0 = fmaf(v1, __int_as_float(p1.y), acc0);
            acc0 = fmaf(v2, __int_as_float(p2.y), acc0);
            acc0 = fmaf(v3, __int_as_float(p3.y), acc0);
        }
    }
    for (; e < e1; ++e) {
        int2 p = e2[e];
        if (FPL == 2) {
            float2 v = *(const float2*)(xin + (size_t)p.x * F + sub * 2);
            acc0 = fmaf(v.x, __int_as_float(p.y), acc0);
            acc1 = fmaf(v.y, __int_as_float(p.y), acc1);
        } else {
            acc0 = fmaf(xin[(size_t)p.x * F + sub], __int_as_float(p.y), acc0);
        }
    }

    float* orow = agg + (size_t)i * F + sub * FPL;
    if (FPL == 2) {
        *(float2*)orow = make_float2(acc0, acc1);
    } else {
        orow[0] = acc0;
    }
}

// register-tiled GEMM: one thread per node. row[FIN] in VGPRs; W/b accesses are
// wave-uniform -> scalar loads (SGPR pipe), no LDS. TN outputs per o-chunk.
template <int FIN, int FOUT, int TN>
__global__ void k_gemm2(const float* __restrict__ agg, const float* __restrict__ W,
                        const float* __restrict__ b, float* __restrict__ out, int n) {
    int i = blockIdx.x * blockDim.x + threadIdx.x;
    if (i >= n) return;
    float row[FIN];
    const float* arow = agg + (size_t)i * FIN;
#pragma unroll
    for (int f = 0; f < FIN; ++f) row[f] = arow[f];
    float* orow = out + (size_t)i * FOUT;
#pragma unroll 1
    for (int oc = 0; oc < FOUT; oc += TN) {
        float acc[TN];
#pragma unroll
        for (int j = 0; j < TN; ++j) acc[j] = b[oc + j];
#pragma unroll
        for (int f = 0; f < FIN; ++f) {
#pragma unroll
            for (int j = 0; j < TN; ++j)
                acc[j] = fmaf(row[f], W[f * FOUT + oc + j], acc[j]);
        }
#pragma unroll
        for (int j = 0; j < TN; ++j) orow[oc + j] = fmaxf(acc[j], 0.0f);
    }
}

extern "C" void kernel_launch(void* const* d_in, const int* in_sizes, int n_in,
                              void* d_out, int out_size, void* d_ws, size_t ws_size,
                              hipStream_t stream) {
    const float* x  = (const float*)d_in[0];
    const int*   ei = (const int*)d_in[1];  // [2][NE]: row0=src, row1=dst
    const float* ew = (const float*)d_in[2];
    const float* W1 = (const float*)d_in[3];
    const float* b1 = (const float*)d_in[4];
    const float* W2 = (const float*)d_in[5];
    const float* b2 = (const float*)d_in[6];
    const float* W3 = (const float*)d_in[7];
    const float* b3 = (const float*)d_in[8];
    float* out = (float*)d_out;

    const int* src = ei;
    const int* dst = ei + NE;

    // workspace layout (512B aligned chunks)
    char* ws = (char*)d_ws;
    size_t off = 0;
    auto alloc = [&](size_t bytes) {
        char* p = ws + off;
        off += (bytes + 511) / 512 * 512;
        return p;
    };
    float* dis    = (float*)alloc((size_t)NN * 4);
    int*   rowptr = (int*)alloc((size_t)(NN + 1) * 4);
    int*   part   = (int*)alloc(512 * 4);
    int2*  e2     = (int2*)alloc((size_t)NE * 8);
    float* bufA   = (float*)alloc((size_t)NN * 54 * 4);
    float* bufB   = (float*)alloc((size_t)NN * 54 * 4);

    // aliases into buf regions (all dead before aggs/gemms start writing bufs):
    unsigned short* rank = (unsigned short*)bufA;  // 6.4MB, dead after k_build
    ull* packed = (ull*)bufB;                      // 6.4MB padded (64B/node), dead after k_finish
    int* cnt    = (int*)((char*)bufB + (size_t)NN * 8 * PSTRIDE);  // 0.4MB, dead after k_scan3

    const int B = 256;
    const int NBLK = cdiv(NN, SCAN_CHUNK);  // 391

    // ---- norm + CSR build ----
    k_init<<<cdiv((long long)NN * PSTRIDE, B), B, 0, stream>>>(packed, NN * PSTRIDE);
    k_deg_hist<<<cdiv(NE, B), B, 0, stream>>>(dst, ew, packed, rank, NE);
    k_finish<<<cdiv(NN, B), B, 0, stream>>>(packed, dis, cnt, NN);
    k_scan1<<<NBLK, SCAN_CHUNK, 0, stream>>>(cnt, part, NN);
    k_scan2<<<1, 512, 0, stream>>>(part, NBLK);
    k_scan3<<<NBLK, SCAN_CHUNK, 0, stream>>>(cnt, part, rowptr, NN);
    k_build<<<cdiv(NE, B), B, 0, stream>>>(src, dst, ew, dis, rank, rowptr, e2, NE);

    // nodes per block for each agg config
    const int NPB9  = (64 / (9 / 1)) * 4;   // 28
    const int NPB18 = (64 / (18 / 2)) * 4;  // 28
    const int NPB54 = (64 / (54 / 2)) * 4;  // 8

    // ---- layer 1: agg(x, F=9) -> gemm 9x18 -> bufB ----
    k_agg2<9, 1><<<cdiv(NN, NPB9), B, 0, stream>>>(x, dis, rowptr, e2, bufA, NN);
    k_gemm2<9, 18, 6><<<cdiv(NN, B), B, 0, stream>>>(bufA, W1, b1, bufB, NN);

    // ---- layer 2: agg(bufB, F=18) -> gemm 18x54 -> bufB ----
    k_agg2<18, 2><<<cdiv(NN, NPB18), B, 0, stream>>>(bufB, dis, rowptr, e2, bufA, NN);
    k_gemm2<18, 54, 6><<<cdiv(NN, B), B, 0, stream>>>(bufA, W2, b2, bufB, NN);

    // ---- layer 3: agg(bufB, F=54) -> gemm 54x108 -> d_out ----
    k_agg2<54, 2><<<cdiv(NN, NPB54), B, 0, stream>>>(bufB, dis, rowptr, e2, bufA, NN);
    k_gemm2<54, 108, 6><<<cdiv(NN, B), B, 0, stream>>>(bufA, W3, b3, out, NN);
}

// Round 9
// 440.002 us; speedup vs baseline: 4.1124x; 1.2535x over previous
//
#include <hip/hip_runtime.h>

#define NN 100000
#define NE 3200000
#define NB 391      // buckets: dst>>8, ceil(100000/256)
#define BCAP 9216   // bucket capacity: mean 8184, +11 sigma
#define EPB 8192    // edges per scatter block (32 per thread)

static inline int cdiv(long long a, int b) { return (int)((a + b - 1) / b); }

// bsize = 0; rowptr[NN] = NE (never touched elsewhere)
__global__ void k_zero(int* bsize, int* rowptr) {
    int i = blockIdx.x * blockDim.x + threadIdx.x;
    if (i < NB) bsize[i] = 0;
    if (i == NB) rowptr[NN] = NE;
}

// Pass A: bucket edges by dst>>8. LDS histogram -> one global reservation per
// (block,bucket) -> LDS-rank scatter. Record = ((dst&255)<<17 | src, w).
__global__ __launch_bounds__(256) void k_scatterB(
    const int* __restrict__ dst, const int* __restrict__ src, const float* __restrict__ w,
    int* __restrict__ bsize, int2* __restrict__ barr) {
    __shared__ int hcnt[NB];
    __shared__ int hbase[NB];
    int t = threadIdx.x;
    for (int b = t; b < NB; b += 256) hcnt[b] = 0;
    __syncthreads();
    int base = blockIdx.x * EPB;
    // count
    for (int k = 0; k < 32; ++k) {
        int e = base + t + (k << 8);
        if (e < NE) atomicAdd(&hcnt[dst[e] >> 8], 1);
    }
    __syncthreads();
    // reserve per-bucket chunks
    for (int b = t; b < NB; b += 256) {
        int c = hcnt[b];
        hbase[b] = (c > 0) ? atomicAdd(&bsize[b], c) : 0;
    }
    __syncthreads();
    for (int b = t; b < NB; b += 256) hcnt[b] = 0;
    __syncthreads();
    // rank + scatter (any within-bucket permutation is valid)
    for (int k = 0; k < 32; ++k) {
        int e = base + t + (k << 8);
        if (e < NE) {
            int d = dst[e];
            int bk = d >> 8;
            int rk = atomicAdd(&hcnt[bk], 1);
            int pos = hbase[bk] + rk;
            if (pos < BCAP) {
                int key = ((d & 255) << 17) | src[e];
                barr[(size_t)bk * BCAP + pos] = make_int2(key, __float_as_int(w[e]));
            }
        }
    }
}

// exclusive scan of bucket sizes -> bucket edge bases
__global__ void k_scanBB(const int* __restrict__ bsize, int* __restrict__ bbase) {
    __shared__ int s[512];
    int t = threadIdx.x;
    int v = (t < NB) ? bsize[t] : 0;
    s[t] = v;
    __syncthreads();
    for (int d = 1; d < 512; d <<= 1) {
        int a = (t >= d) ? s[t - d] : 0;
        __syncthreads();
        s[t] += a;
        __syncthreads();
    }
    if (t < NB) bbase[t] = s[t] - v;
}

// Pass B: one block per bucket. LDS count+wsum -> scan -> rowptr/dis; then
// LDS-rank CSR fill. e2 record = (src, w) — no dis needed (norm factored out).
__global__ __launch_bounds__(256) void k_bucketCSR(
    const int2* __restrict__ barr, const int* __restrict__ bsize, const int* __restrict__ bbase,
    int* __restrict__ rowptr, float* __restrict__ dis, int2* __restrict__ e2) {
    __shared__ int cnt[256];
    __shared__ float wsum[256];
    __shared__ int rbase[256];
    __shared__ int sc[256];
    int b = blockIdx.x;
    int t = threadIdx.x;
    int nE = bsize[b];
    int ebase = bbase[b];
    const int2* rec = barr + (size_t)b * BCAP;
    cnt[t] = 0;
    wsum[t] = 0.0f;
    __syncthreads();
    for (int e = t; e < nE; e += 256) {
        int2 r = rec[e];
        int dl = (r.x >> 17) & 255;
        atomicAdd(&cnt[dl], 1);
        atomicAdd(&wsum[dl], __int_as_float(r.y));
    }
    __syncthreads();
    int v = cnt[t];
    sc[t] = v;
    __syncthreads();
    for (int d = 1; d < 256; d <<= 1) {
        int a = (t >= d) ? sc[t - d] : 0;
        __syncthreads();
        sc[t] += a;
        __syncthreads();
    }
    rbase[t] = sc[t] - v;  // exclusive within bucket
    int node = (b << 8) + t;
    if (node < NN) {
        rowptr[node] = ebase + rbase[t];
        dis[node] = rsqrtf(1.0f + wsum[t]);
    }
    cnt[t] = 0;
    __syncthreads();
    for (int e = t; e < nE; e += 256) {
        int2 r = rec[e];
        int dl = (r.x >> 17) & 255;
        int rk = atomicAdd(&cnt[dl], 1);
        e2[(size_t)(ebase + rbase[dl] + rk)] = make_int2(r.x & 0x1FFFF, r.y);
    }
}

// y1 = x * dis (broadcast per row), F=9
__global__ void k_scaleY(const float* __restrict__ x, const float* __restrict__ dis,
                         float* __restrict__ yx, int n) {
    int i = blockIdx.x * blockDim.x + threadIdx.x;
    if (i < n * 9) yx[i] = x[i] * dis[i / 9];
}

// gather-aggregate in y-space: out[i] = dis[i] * ( y[i] + sum_e w_e * y[src_e] ).
// F = feature dim, FPL = floats per lane; LPN lanes/node, NPW nodes/wave, 4 waves/block.
template <int F, int FPL>
__global__ void k_agg3(const float* __restrict__ yin, const float* __restrict__ dis,
                       const int* __restrict__ rowptr, const int2* __restrict__ e2,
                       float* __restrict__ agg, int n) {
    constexpr int LPN = F / FPL;
    constexpr int NPW = 64 / LPN;
    int wv = threadIdx.x >> 6;
    int l = threadIdx.x & 63;
    int ni = l / LPN;
    int sub = l - ni * LPN;
    if (ni >= NPW) return;
    int i = (blockIdx.x * 4 + wv) * NPW + ni;
    if (i >= n) return;

    const float* yrow = yin + (size_t)i * F + sub * FPL;
    float acc0 = yrow[0];
    float acc1 = (FPL == 2) ? yrow[1] : 0.0f;

    int e0 = rowptr[i];
    int e1 = rowptr[i + 1];
    int e = e0;
    for (; e + 4 <= e1; e += 4) {
        int2 p0 = e2[e + 0];
        int2 p1 = e2[e + 1];
        int2 p2 = e2[e + 2];
        int2 p3 = e2[e + 3];
        if (FPL == 2) {
            float2 v0 = *(const float2*)(yin + (size_t)p0.x * F + sub * 2);
            float2 v1 = *(const float2*)(yin + (size_t)p1.x * F + sub * 2);
            float2 v2 = *(const float2*)(yin + (size_t)p2.x * F + sub * 2);
            float2 v3 = *(const float2*)(yin + (size_t)p3.x * F + sub * 2);
            acc0 = fmaf(v0.x, __int_as_float(p0.y), acc0);
            acc1 = fmaf(v0.y, __int_as_float(p0.y), acc1);
            acc0 = fmaf(v1.x, __int_as_float(p1.y), acc0);
            acc1 = fmaf(v1.y, __int_as_float(p1.y), acc1);
            acc0 = fmaf(v2.x, __int_as_float(p2.y), acc0);
            acc1 = fmaf(v2.y, __int_as_float(p2.y), acc1);
            acc0 = fmaf(v3.x, __int_as_float(p3.y), acc0);
            acc1 = fmaf(v3.y, __int_as_float(p3.y), acc1);
        } else {
            float v0 = yin[(size_t)p0.x * F + sub];
            float v1 = yin[(size_t)p1.x * F + sub];
            float v2 = yin[(size_t)p2.x * F + sub];
            float v3 = yin[(size_t)p3.x * F + sub];
            acc0 = fmaf(v0, __int_as_float(p0.y), acc0);
            acc0 = fmaf(v1, __int_as_float(p1.y), acc0);
            acc0 = fmaf(v2, __int_as_float(p2.y), acc0);
            acc0 = fmaf(v3, __int_as_float(p3.y), acc0);
        }
    }
    for (; e < e1; ++e) {
        int2 p = e2[e];
        if (FPL == 2) {
            float2 v = *(const float2*)(yin + (size_t)p.x * F + sub * 2);
            acc0 = fmaf(v.x, __int_as_float(p.y), acc0);
            acc1 = fmaf(v.y, __int_as_float(p.y), acc1);
        } else {
            acc0 = fmaf(yin[(size_t)p.x * F + sub], __int_as_float(p.y), acc0);
        }
    }

    float di = dis[i];
    float* orow = agg + (size_t)i * F + sub * FPL;
    if (FPL == 2) {
        *(float2*)orow = make_float2(acc0 * di, acc1 * di);
    } else {
        orow[0] = acc0 * di;
    }
}

// register-tiled GEMM, one thread per node; W/b wave-uniform -> scalar loads.
// SCALE: epilogue multiplies by dis[i] (produces y-space for the next layer).
template <int FIN, int FOUT, int TN, bool SCALE>
__global__ void k_gemm3(const float* __restrict__ agg, const float* __restrict__ W,
                        const float* __restrict__ bias, const float* __restrict__ dis,
                        float* __restrict__ outp, int n) {
    int i = blockIdx.x * blockDim.x + threadIdx.x;
    if (i >= n) return;
    float row[FIN];
    const float* arow = agg + (size_t)i * FIN;
#pragma unroll
    for (int f = 0; f < FIN; ++f) row[f] = arow[f];
    float sc = SCALE ? dis[i] : 1.0f;
    float* orow = outp + (size_t)i * FOUT;
#pragma unroll 1
    for (int oc = 0; oc < FOUT; oc += TN) {
        float acc[TN];
#pragma unroll
        for (int j = 0; j < TN; ++j) acc[j] = bias[oc + j];
#pragma unroll
        for (int f = 0; f < FIN; ++f) {
#pragma unroll
            for (int j = 0; j < TN; ++j)
                acc[j] = fmaf(row[f], W[f * FOUT + oc + j], acc[j]);
        }
#pragma unroll
        for (int j = 0; j < TN; ++j) orow[oc + j] = fmaxf(acc[j], 0.0f) * sc;
    }
}

extern "C" void kernel_launch(void* const* d_in, const int* in_sizes, int n_in,
                              void* d_out, int out_size, void* d_ws, size_t ws_size,
                              hipStream_t stream) {
    const float* x  = (const float*)d_in[0];
    const int*   ei = (const int*)d_in[1];  // [2][NE]: row0=src, row1=dst
    const float* ew = (const float*)d_in[2];
    const float* W1 = (const float*)d_in[3];
    const float* b1 = (const float*)d_in[4];
    const float* W2 = (const float*)d_in[5];
    const float* b2 = (const float*)d_in[6];
    const float* W3 = (const float*)d_in[7];
    const float* b3 = (const float*)d_in[8];
    float* out = (float*)d_out;

    const int* src = ei;
    const int* dst = ei + NE;

    // workspace layout (512B aligned chunks)
    char* ws = (char*)d_ws;
    size_t off = 0;
    auto alloc = [&](size_t bytes) {
        char* p = ws + off;
        off += (bytes + 511) / 512 * 512;
        return p;
    };
    float* dis    = (float*)alloc((size_t)NN * 4);
    int*   rowptr = (int*)alloc((size_t)(NN + 1) * 4);
    int*   bsize  = (int*)alloc(NB * 4);
    int*   bbase  = (int*)alloc(NB * 4);
    int2*  e2     = (int2*)alloc((size_t)NE * 8);
    float* yx     = (float*)alloc((size_t)NN * 9 * 4);
    float* bufA   = (float*)alloc((size_t)NN * 54 * 4);
    float* bufB   = (float*)alloc((size_t)NN * 54 * 4);

    // bucket scatter array (28.8MB) aliases bufA/bufB (43.2MB): dead before agg1.
    int2* barr = (int2*)bufA;

    const int B = 256;

    // ---- CSR build (bucketed, LDS atomics) ----
    k_zero<<<2, B, 0, stream>>>(bsize, rowptr);
    k_scatterB<<<cdiv(NE, EPB), B, 0, stream>>>(dst, src, ew, bsize, barr);
    k_scanBB<<<1, 512, 0, stream>>>(bsize, bbase);
    k_bucketCSR<<<NB, B, 0, stream>>>(barr, bsize, bbase, rowptr, dis, e2);

    // ---- y1 = x * dis ----
    k_scaleY<<<cdiv((long long)NN * 9, B), B, 0, stream>>>(x, dis, yx, NN);

    // nodes per block for each agg config
    const int NPB9  = (64 / 9) * 4;        // 28
    const int NPB18 = (64 / (18 / 2)) * 4; // 28
    const int NPB54 = (64 / (54 / 2)) * 4; // 8

    // ---- layer 1: agg(y1, F=9) -> gemm 9x18 (scale) -> bufB (=y2) ----
    k_agg3<9, 1><<<cdiv(NN, NPB9), B, 0, stream>>>(yx, dis, rowptr, e2, bufA, NN);
    k_gemm3<9, 18, 6, true><<<cdiv(NN, B), B, 0, stream>>>(bufA, W1, b1, dis, bufB, NN);

    // ---- layer 2: agg(y2, F=18) -> gemm 18x54 (scale) -> bufB (=y3) ----
    k_agg3<18, 2><<<cdiv(NN, NPB18), B, 0, stream>>>(bufB, dis, rowptr, e2, bufA, NN);
    k_gemm3<18, 54, 6, true><<<cdiv(NN, B), B, 0, stream>>>(bufA, W2, b2, dis, bufB, NN);

    // ---- layer 3: agg(y3, F=54) -> gemm 54x108 (no scale) -> out ----
    k_agg3<54, 2><<<cdiv(NN, NPB54), B, 0, stream>>>(bufB, dis, rowptr, e2, bufA, NN);
    k_gemm3<54, 108, 6, false><<<cdiv(NN, B), B, 0, stream>>>(bufA, W3, b3, dis, out, NN);
}

// Round 10
// 375.901 us; speedup vs baseline: 4.8137x; 1.1705x over previous
//
#include <hip/hip_runtime.h>

#define NN 100000
#define NE 3200000
#define NB 391      // buckets: dst>>8
#define BCAP 9216   // bucket capacity: mean 8184, +11 sigma
#define EPB 8192    // edges per scatter block

static inline int cdiv(long long a, int b) { return (int)((a + b - 1) / b); }

__global__ void k_zero(int* bsize, int* rowptr) {
    int i = blockIdx.x * blockDim.x + threadIdx.x;
    if (i < NB) bsize[i] = 0;
    if (i == NB) rowptr[NN] = NE;
}

// Pass A: bucket edges by dst>>8. LDS histogram -> global reservation -> scatter.
__global__ __launch_bounds__(256) void k_scatterB(
    const int* __restrict__ dst, const int* __restrict__ src, const float* __restrict__ w,
    int* __restrict__ bsize, int2* __restrict__ barr) {
    __shared__ int hcnt[NB];
    __shared__ int hbase[NB];
    int t = threadIdx.x;
    for (int b = t; b < NB; b += 256) hcnt[b] = 0;
    __syncthreads();
    int base = blockIdx.x * EPB;
    for (int k = 0; k < 32; ++k) {
        int e = base + t + (k << 8);
        if (e < NE) atomicAdd(&hcnt[dst[e] >> 8], 1);
    }
    __syncthreads();
    for (int b = t; b < NB; b += 256) {
        int c = hcnt[b];
        hbase[b] = (c > 0) ? atomicAdd(&bsize[b], c) : 0;
    }
    __syncthreads();
    for (int b = t; b < NB; b += 256) hcnt[b] = 0;
    __syncthreads();
    for (int k = 0; k < 32; ++k) {
        int e = base + t + (k << 8);
        if (e < NE) {
            int d = dst[e];
            int bk = d >> 8;
            int rk = atomicAdd(&hcnt[bk], 1);
            int pos = hbase[bk] + rk;
            if (pos < BCAP) {
                int key = ((d & 255) << 17) | src[e];
                barr[(size_t)bk * BCAP + pos] = make_int2(key, __float_as_int(w[e]));
            }
        }
    }
}

__global__ void k_scanBB(const int* __restrict__ bsize, int* __restrict__ bbase) {
    __shared__ int s[512];
    int t = threadIdx.x;
    int v = (t < NB) ? bsize[t] : 0;
    s[t] = v;
    __syncthreads();
    for (int d = 1; d < 512; d <<= 1) {
        int a = (t >= d) ? s[t - d] : 0;
        __syncthreads();
        s[t] += a;
        __syncthreads();
    }
    if (t < NB) bbase[t] = s[t] - v;
}

// Pass B: one block per bucket. LDS count+wsum -> scan -> rowptr/dis; CSR fill.
__global__ __launch_bounds__(256) void k_bucketCSR(
    const int2* __restrict__ barr, const int* __restrict__ bsize, const int* __restrict__ bbase,
    int* __restrict__ rowptr, float* __restrict__ dis, int2* __restrict__ e2) {
    __shared__ int cnt[256];
    __shared__ float wsum[256];
    __shared__ int rbase[256];
    __shared__ int sc[256];
    int b = blockIdx.x;
    int t = threadIdx.x;
    int nE = bsize[b];
    int ebase = bbase[b];
    const int2* rec = barr + (size_t)b * BCAP;
    cnt[t] = 0;
    wsum[t] = 0.0f;
    __syncthreads();
    for (int e = t; e < nE; e += 256) {
        int2 r = rec[e];
        int dl = (r.x >> 17) & 255;
        atomicAdd(&cnt[dl], 1);
        atomicAdd(&wsum[dl], __int_as_float(r.y));
    }
    __syncthreads();
    int v = cnt[t];
    sc[t] = v;
    __syncthreads();
    for (int d = 1; d < 256; d <<= 1) {
        int a = (t >= d) ? sc[t - d] : 0;
        __syncthreads();
        sc[t] += a;
        __syncthreads();
    }
    rbase[t] = sc[t] - v;
    int node = (b << 8) + t;
    if (node < NN) {
        rowptr[node] = ebase + rbase[t];
        dis[node] = rsqrtf(1.0f + wsum[t]);
    }
    cnt[t] = 0;
    __syncthreads();
    for (int e = t; e < nE; e += 256) {
        int2 r = rec[e];
        int dl = (r.x >> 17) & 255;
        int rk = atomicAdd(&cnt[dl], 1);
        e2[(size_t)(ebase + rbase[dl] + rk)] = make_int2(r.x & 0x1FFFF, r.y);
    }
}

// y1[i][f] = x[i][f] * dis[i], padded stride 16
__global__ void k_scaleY(const float* __restrict__ x, const float* __restrict__ dis,
                         float* __restrict__ yx, int n) {
    int t = blockIdx.x * blockDim.x + threadIdx.x;
    if (t < n * 9) {
        int i = t / 9;
        int f = t - i * 9;
        yx[(size_t)i * 16 + f] = x[t] * dis[i];
    }
}

// gather-aggregate in y-space, padded gather stride YS (power of 2):
// out[i] = dis[i] * ( y[i] + sum_e w_e * y[src_e] ).  Output stride = F (unpadded).
template <int F, int FPL, int YS>
__global__ void k_agg3(const float* __restrict__ yin, const float* __restrict__ dis,
                       const int* __restrict__ rowptr, const int2* __restrict__ e2,
                       float* __restrict__ agg, int n) {
    constexpr int LPN = F / FPL;
    constexpr int NPW = 64 / LPN;
    int wv = threadIdx.x >> 6;
    int l = threadIdx.x & 63;
    int ni = l / LPN;
    int sub = l - ni * LPN;
    if (ni >= NPW) return;
    int i = (blockIdx.x * 4 + wv) * NPW + ni;
    if (i >= n) return;

    const float* yrow = yin + (size_t)i * YS + sub * FPL;
    float acc0 = yrow[0];
    float acc1 = (FPL == 2) ? yrow[1] : 0.0f;

    int e0 = rowptr[i];
    int e1 = rowptr[i + 1];
    int e = e0;
    for (; e + 4 <= e1; e += 4) {
        int2 p0 = e2[e + 0];
        int2 p1 = e2[e + 1];
        int2 p2 = e2[e + 2];
        int2 p3 = e2[e + 3];
        if (FPL == 2) {
            float2 v0 = *(const float2*)(yin + (size_t)p0.x * YS + sub * 2);
            float2 v1 = *(const float2*)(yin + (size_t)p1.x * YS + sub * 2);
            float2 v2 = *(const float2*)(yin + (size_t)p2.x * YS + sub * 2);
            float2 v3 = *(const float2*)(yin + (size_t)p3.x * YS + sub * 2);
            acc0 = fmaf(v0.x, __int_as_float(p0.y), acc0);
            acc1 = fmaf(v0.y, __int_as_float(p0.y), acc1);
            acc0 = fmaf(v1.x, __int_as_float(p1.y), acc0);
            acc1 = fmaf(v1.y, __int_as_float(p1.y), acc1);
            acc0 = fmaf(v2.x, __int_as_float(p2.y), acc0);
            acc1 = fmaf(v2.y, __int_as_float(p2.y), acc1);
            acc0 = fmaf(v3.x, __int_as_float(p3.y), acc0);
            acc1 = fmaf(v3.y, __int_as_float(p3.y), acc1);
        } else {
            float v0 = yin[(size_t)p0.x * YS + sub];
            float v1 = yin[(size_t)p1.x * YS + sub];
            float v2 = yin[(size_t)p2.x * YS + sub];
            float v3 = yin[(size_t)p3.x * YS + sub];
            acc0 = fmaf(v0, __int_as_float(p0.y), acc0);
            acc0 = fmaf(v1, __int_as_float(p1.y), acc0);
            acc0 = fmaf(v2, __int_as_float(p2.y), acc0);
            acc0 = fmaf(v3, __int_as_float(p3.y), acc0);
        }
    }
    for (; e < e1; ++e) {
        int2 p = e2[e];
        if (FPL == 2) {
            float2 v = *(const float2*)(yin + (size_t)p.x * YS + sub * 2);
            acc0 = fmaf(v.x, __int_as_float(p.y), acc0);
            acc1 = fmaf(v.y, __int_as_float(p.y), acc1);
        } else {
            acc0 = fmaf(yin[(size_t)p.x * YS + sub], __int_as_float(p.y), acc0);
        }
    }

    float di = dis[i];
    float* orow = agg + (size_t)i * F + sub * FPL;
    if (FPL == 2) {
        *(float2*)orow = make_float2(acc0 * di, acc1 * di);
    } else {
        orow[0] = acc0 * di;
    }
}

// Register-tiled GEMM with output-split across waves for occupancy.
// Wave-uniform output chunk j (readfirstlane -> SGPR W/bias loads).
// OS = output row stride (padded y-space or dense out). CH = FOUT/OSPLIT.
template <int FIN, int FOUT, int OSPLIT, int OS, bool SCALE>
__global__ __launch_bounds__(256) void k_gemm4(
    const float* __restrict__ agg, const float* __restrict__ W,
    const float* __restrict__ bias, const float* __restrict__ dis,
    float* __restrict__ outp, int n) {
    constexpr int CH = FOUT / OSPLIT;
    constexpr int NGRP = 4 / OSPLIT;  // node-groups (of 64) per block
    int wv = threadIdx.x >> 6;
    int l = threadIdx.x & 63;
    int j = __builtin_amdgcn_readfirstlane(wv & (OSPLIT - 1));
    int grp = wv >> ((OSPLIT == 4) ? 2 : (OSPLIT == 2) ? 1 : 0);
    int i = (blockIdx.x * NGRP + grp) * 64 + l;
    if (i >= n) return;

    float row[FIN];
    const float* arow = agg + (size_t)i * FIN;
#pragma unroll
    for (int f = 0; f < FIN; ++f) row[f] = arow[f];
    float sc = SCALE ? dis[i] : 1.0f;
    const float* Wj = W + j * CH;
    const float* bj = bias + j * CH;
    float acc[CH];
#pragma unroll
    for (int jj = 0; jj < CH; ++jj) acc[jj] = bj[jj];
#pragma unroll
    for (int f = 0; f < FIN; ++f) {
#pragma unroll
        for (int jj = 0; jj < CH; ++jj)
            acc[jj] = fmaf(row[f], Wj[f * FOUT + jj], acc[jj]);
    }
    float* orow = outp + (size_t)i * OS + j * CH;
#pragma unroll
    for (int jj = 0; jj < CH; ++jj) orow[jj] = fmaxf(acc[jj], 0.0f) * sc;
}

extern "C" void kernel_launch(void* const* d_in, const int* in_sizes, int n_in,
                              void* d_out, int out_size, void* d_ws, size_t ws_size,
                              hipStream_t stream) {
    const float* x  = (const float*)d_in[0];
    const int*   ei = (const int*)d_in[1];  // [2][NE]: row0=src, row1=dst
    const float* ew = (const float*)d_in[2];
    const float* W1 = (const float*)d_in[3];
    const float* b1 = (const float*)d_in[4];
    const float* W2 = (const float*)d_in[5];
    const float* b2 = (const float*)d_in[6];
    const float* W3 = (const float*)d_in[7];
    const float* b3 = (const float*)d_in[8];
    float* out = (float*)d_out;

    const int* src = ei;
    const int* dst = ei + NE;

    // workspace layout (512B aligned chunks)
    char* ws = (char*)d_ws;
    size_t off = 0;
    auto alloc = [&](size_t bytes) {
        char* p = ws + off;
        off += (bytes + 511) / 512 * 512;
        return p;
    };
    float* dis    = (float*)alloc((size_t)NN * 4);
    int*   rowptr = (int*)alloc((size_t)(NN + 1) * 4);
    int*   bsize  = (int*)alloc(NB * 4);
    int*   bbase  = (int*)alloc(NB * 4);
    int2*  e2     = (int2*)alloc((size_t)NE * 8);
    float* bufA   = (float*)alloc((size_t)NN * 54 * 4);   // agg output (dense)
    float* bufB   = (float*)alloc((size_t)NN * 64 * 4);   // y-space (padded, stride<=64)

    // aliases (dead-region proofs):
    // barr: 28.8MB from bufA start (spans 7.2MB into bufB) — dead after k_bucketCSR,
    //   before any agg/gemm writes bufA/bufB.
    // yx (y1, stride 16, 6.4MB): at bufB+12.8MB — beyond barr's span; dead after agg1;
    //   gemm1 writes only bufB[0..12.8MB) (y2, stride 32).
    int2*  barr = (int2*)bufA;
    float* yx   = (float*)((char*)bufB + (size_t)NN * 32 * 4);

    const int B = 256;

    // ---- CSR build (bucketed, LDS atomics) ----
    k_zero<<<2, B, 0, stream>>>(bsize, rowptr);
    k_scatterB<<<cdiv(NE, EPB), B, 0, stream>>>(dst, src, ew, bsize, barr);
    k_scanBB<<<1, 512, 0, stream>>>(bsize, bbase);
    k_bucketCSR<<<NB, B, 0, stream>>>(barr, bsize, bbase, rowptr, dis, e2);

    // ---- y1 = x * dis (stride 16) ----
    k_scaleY<<<cdiv((long long)NN * 9, B), B, 0, stream>>>(x, dis, yx, NN);

    // nodes per block for each agg config
    const int NPB9  = (64 / 9) * 4;        // 28
    const int NPB18 = (64 / (18 / 2)) * 4; // 28
    const int NPB54 = (64 / (54 / 2)) * 4; // 8

    // ---- layer 1: agg(y1) -> gemm 9x18 (scale) -> bufB y2 (stride 32) ----
    k_agg3<9, 1, 16><<<cdiv(NN, NPB9), B, 0, stream>>>(yx, dis, rowptr, e2, bufA, NN);
    k_gemm4<9, 18, 2, 32, true><<<cdiv(NN, 128), B, 0, stream>>>(bufA, W1, b1, dis, bufB, NN);

    // ---- layer 2: agg(y2) -> gemm 18x54 (scale) -> bufB y3 (stride 64) ----
    k_agg3<18, 2, 32><<<cdiv(NN, NPB18), B, 0, stream>>>(bufB, dis, rowptr, e2, bufA, NN);
    k_gemm4<18, 54, 2, 64, true><<<cdiv(NN, 128), B, 0, stream>>>(bufA, W2, b2, dis, bufB, NN);

    // ---- layer 3: agg(y3) -> gemm 54x108 (no scale) -> out (dense 108) ----
    k_agg3<54, 2, 64><<<cdiv(NN, NPB54), B, 0, stream>>>(bufB, dis, rowptr, e2, bufA, NN);
    k_gemm4<54, 108, 4, 108, false><<<cdiv(NN, 64), B, 0, stream>>>(bufA, W3, b3, dis, out, NN);
}